// Round 13
// baseline (174.581 us; speedup 1.0000x reference)
//
#include <hip/hip_runtime.h>

typedef __attribute__((ext_vector_type(8)))  short  short8;
typedef __attribute__((ext_vector_type(16))) float  f32x16;
typedef __attribute__((ext_vector_type(4)))  float  flt4;
typedef __attribute__((ext_vector_type(2)))  float  flt2;
typedef __attribute__((ext_vector_type(4)))  unsigned int u32x4;

#define T_DIM 16384
#define C_DIM 768
#define O_DIM 768

// ---- K layout: per 16-c chunk, 144 k-columns = [16 silu][16c x 8 spline slots]
#define CK2    16
#define CHUNKS 48
#define KSTEPS 9
#define NSG    432            // CHUNKS*KSTEPS
#define LDA3   152            // 144 + 8 pad shorts (304 B row)
#define BM     64
#define BN     768
#define LDSBUF 19456          // BM * 304 bytes per A-buffer
#define WT3_BYTES  ((size_t)NSG * 12288 * 2)

__device__ __forceinline__ unsigned short f2bf(float f) {
  unsigned u = __float_as_uint(f);
  return (unsigned short)((u + 0x7FFFu + ((u >> 16) & 1u)) >> 16);
}

__device__ __forceinline__ unsigned cvtpk(float lo, float hi) {
  unsigned r;
  asm("v_cvt_pk_bf16_f32 %0, %1, %2" : "=v"(r) : "v"(lo), "v"(hi));
  return r;
}

// ---------------- prep: combined bf16 weights, fragment-major ---------------
// k_silu(c)     = (c>>4)*144 + (c&15)
// k_spline(c,s) = (c>>4)*144 + 16 + (c&15)*8 + s
// phys short index = (k>>4)*12288 + o*16 + (k&15)
__global__ void kan_prep3(const float* __restrict__ bw, const float* __restrict__ sw,
                          const float* __restrict__ sc, unsigned short* __restrict__ wt) {
  int id = blockIdx.x * 256 + threadIdx.x;
  if (id >= O_DIM * C_DIM) return;
  int o = id / C_DIM;
  int c = id - o * C_DIM;
  float b = bw[id];
  float s = sc[id];
  const float* sp = sw + (size_t)id * 8;
  {
    int k = (c >> 4) * 144 + (c & 15);
    wt[(size_t)(k >> 4) * 12288 + o * 16 + (k & 15)] = f2bf(b);
  }
#pragma unroll
  for (int g = 0; g < 8; ++g) {
    int k = (c >> 4) * 144 + 16 + (c & 15) * 8 + g;
    wt[(size_t)(k >> 4) * 12288 + o * 16 + (k & 15)] = f2bf(sp[g] * s);
  }
}

// ---------------- fused GEMM (ws path) --------------------------------------
// Round-9 structure (best: 167us): 512 threads = 8 waves of 64x96; block tile
// 64x768 (full O); grid 256 = 1 block/CU; x staged exactly once device-wide.
// THIS ROUND: no setprio (m190: hurts lockstep GEMM); KSTEP rewritten as a
// 1:1 MFMA<->load interleave (AITER s02 pattern) so sibling waves on a SIMD
// can slot their MFMAs into each other's load/VALU gaps.
__global__ __launch_bounds__(512, 2) void kan_gemm12(
    const float* __restrict__ x, const unsigned short* __restrict__ wt,
    float* __restrict__ out) {
  __shared__ short Alds[2 * BM * LDA3];   // 38912 B

  const int tid  = threadIdx.x;
  const int lane = tid & 63;
  const int wn   = tid >> 6;            // wave 0..7 -> 96-col slab
  const int l31  = lane & 31;
  const int lq   = lane >> 5;

  const int d  = blockIdx.x;            // 0..255
  const int tBase = d * BM;
  const int oBase = wn * 96;

  f32x16 acc[2][3];
#pragma unroll
  for (int a = 0; a < 2; ++a)
#pragma unroll
    for (int b = 0; b < 3; ++b)
#pragma unroll
      for (int r = 0; r < 16; ++r) acc[a][b][r] = 0.0f;

  // staging: thread -> (row 0..63, 2-col pair); 2 elements per chunk
  const int sRow = tid >> 3;            // 0..63
  const int sSb  = tid & 7;             // 0..7  -> c pair sSb*2 + {0,1}
  const float* xrow = x + (size_t)(tBase + sRow) * C_DIM + sSb * 2;

  char* ldsB = (char*)Alds;
  const int wbase = sRow * 304;
  int rbyte[2];
#pragma unroll
  for (int mf = 0; mf < 2; ++mf)
    rbyte[mf] = (mf * 32 + l31) * 304 + lq * 16;

  flt2 xa = *(const flt2*)(xrow);       // x for chunk 0
  float    su[2];                       // silu values (2 c)
  unsigned sww[8];                      // spline words, 4 per c

  auto stage_j = [&](int j) {
    float xx  = xa[j];
    float ex  = __expf(-xx);
    float sig = __builtin_amdgcn_rcpf(1.0f + ex);
    su[j] = xx * sig;
    float u  = fmaf(xx, 2.5f, 5.5f);
    float fl = floorf(u);
    int   jj = (int)fl;
    float f  = u - fl;
    float f2 = f * f, f3 = f2 * f;
    float W0 = f3 * (1.0f / 6.0f);
    float om = 1.0f - f;
    float W3 = om * om * om * (1.0f / 6.0f);
    float W2 = 0.5f * f3 - f2 + (2.0f / 3.0f);
    float W1 = 1.0f - W0 - W2 - W3;
    unsigned V0 = cvtpk(W3, W2);
    unsigned V1 = cvtpk(W1, W0);
    unsigned A0 = V0 << 16;
    unsigned A1 = (V1 << 16) | (V0 >> 16);
    unsigned A2 = V1 >> 16;
    int  k = jj - 3;
    int  q = k >> 1;
    bool r = (k & 1) != 0;
    unsigned U0 = r ? A0 : V0;
    unsigned U1 = r ? A1 : V1;
    unsigned U2 = r ? A2 : 0u;
#pragma unroll
    for (int p = 0; p < 4; ++p)
      sww[4 * j + p] =
          (q == p) ? U0 : ((q == p - 1) ? U1 : ((q == p - 2) ? U2 : 0u));
  };

// WR=0: silu b32 (2 shorts); WR=1: spline b128 c0; WR=2: spline b128 c1
#define WRITE_ONE(WR, WOFF)                                             \
  {                                                                     \
    if ((WR) == 0) {                                                    \
      *(unsigned*)(ldsB + (WOFF) + wbase + sSb * 4) = cvtpk(su[0], su[1]); \
    } else {                                                            \
      u32x4 t;                                                          \
      t.x = sww[4 * ((WR) - 1)];     t.y = sww[4 * ((WR) - 1) + 1];     \
      t.z = sww[4 * ((WR) - 1) + 2]; t.w = sww[4 * ((WR) - 1) + 3];     \
      *(u32x4*)(ldsB + (WOFF) + wbase + 32 + sSb * 32 + ((WR) - 1) * 16) = t; \
    }                                                                   \
  }

  // ---- prologue: stage chunk 0 into buf 0, prefetch x(ch1), B sg0/1/2 ----
  stage_j(0); stage_j(1);
  WRITE_ONE(0, 0) WRITE_ONE(1, 0) WRITE_ONE(2, 0)
  xa = *(const flt2*)(xrow + CK2);

  const size_t lofs = (size_t)(oBase + l31) * 16 + lq * 8;
  short8 bb0[3], bb1[3], bb2[3];
  {
    const unsigned short* w0 = wt + lofs;
    bb0[0] = *(const short8*)(w0);
    bb0[1] = *(const short8*)(w0 + 512);
    bb0[2] = *(const short8*)(w0 + 1024);
    const unsigned short* w1 = wt + 12288 + lofs;
    bb1[0] = *(const short8*)(w1);
    bb1[1] = *(const short8*)(w1 + 512);
    bb1[2] = *(const short8*)(w1 + 1024);
    const unsigned short* w2 = wt + 24576 + lofs;
    bb2[0] = *(const short8*)(w2);
    bb2[1] = *(const short8*)(w2 + 512);
    bb2[2] = *(const short8*)(w2 + 1024);
  }
  __syncthreads();

#define LDSA(MF, KS) (*(const short8*)(ldsB + roff + rbyte[MF] + (KS) * 32))
#define MFMA(A, B, C) __builtin_amdgcn_mfma_f32_32x32x16_bf16((A), (B), (C), 0, 0, 0)

  short8 aa0[2], aa1[2];

// KSTEP: 1:1 interleave. BB[j] reloaded only after its last consumer.
#define KSTEP(KS, BB, AAC, AAN, DOREAD, SJ, WR, DOX, GUARD)              \
  {                                                                      \
    if (DOREAD) AAN[0] = LDSA(0, (KS) + 1);                              \
    acc[0][0] = MFMA(AAC[0], BB[0], acc[0][0]);                          \
    if (DOREAD) AAN[1] = LDSA(1, (KS) + 1);                              \
    acc[0][1] = MFMA(AAC[0], BB[1], acc[0][1]);                          \
    acc[0][2] = MFMA(AAC[0], BB[2], acc[0][2]);                          \
    acc[1][0] = MFMA(AAC[1], BB[0], acc[1][0]);                          \
    const unsigned short* wp =                                           \
        wt + (size_t)(chBase + (KS) + 3) * 12288 + lofs;                 \
    const bool bld = !(GUARD) || (chBase + (KS) + 3 < NSG);              \
    if (bld) BB[0] = *(const short8*)(wp);                               \
    acc[1][1] = MFMA(AAC[1], BB[1], acc[1][1]);                          \
    if (bld) BB[1] = *(const short8*)(wp + 512);                         \
    acc[1][2] = MFMA(AAC[1], BB[2], acc[1][2]);                          \
    if (bld) BB[2] = *(const short8*)(wp + 1024);                        \
    if ((WR) >= 0) WRITE_ONE(WR, woff)                                   \
    if ((SJ) >= 0) stage_j(SJ);                                          \
    if (DOX) xa = *(const flt2*)(xrow + (ch + 2) * CK2);                 \
  }

  // ---- main loop: chunks 0..46; stage ch+1 into other buffer; 1 barrier ----
  for (int ch = 0; ch < CHUNKS - 1; ++ch) {
    const int chBase = ch * KSTEPS;
    const int roff   = (ch & 1) * LDSBUF;
    const int woff   = roff ^ LDSBUF;
    const bool dox   = (ch + 2 < CHUNKS);
    aa0[0] = LDSA(0, 0);
    aa0[1] = LDSA(1, 0);
    KSTEP(0, bb0, aa0, aa1, 1,  0, -1, false, 0)
    KSTEP(1, bb1, aa1, aa0, 1,  1, -1, false, 0)
    KSTEP(2, bb2, aa0, aa1, 1, -1, -1, dox,   0)
    KSTEP(3, bb0, aa1, aa0, 1, -1, -1, false, 0)
    KSTEP(4, bb1, aa0, aa1, 1, -1,  0, false, 0)
    KSTEP(5, bb2, aa1, aa0, 1, -1,  1, false, 0)
    KSTEP(6, bb0, aa0, aa1, 1, -1,  2, false, 0)
    KSTEP(7, bb1, aa1, aa0, 1, -1, -1, false, 0)
    KSTEP(8, bb2, aa0, aa1, 0, -1, -1, false, 0)
    __syncthreads();
  }
  // ---- last chunk (reads buf 1; no staging; guard tail B loads) ----
  {
    const int ch     = CHUNKS - 1;
    (void)ch;
    const int chBase = (CHUNKS - 1) * KSTEPS;
    const int roff   = ((CHUNKS - 1) & 1) * LDSBUF;
    const int woff   = 0;  // unused (no WR in tail)
    (void)woff;
    aa0[0] = LDSA(0, 0);
    aa0[1] = LDSA(1, 0);
    KSTEP(0, bb0, aa0, aa1, 1, -1, -1, false, 1)
    KSTEP(1, bb1, aa1, aa0, 1, -1, -1, false, 1)
    KSTEP(2, bb2, aa0, aa1, 1, -1, -1, false, 1)
    KSTEP(3, bb0, aa1, aa0, 1, -1, -1, false, 1)
    KSTEP(4, bb1, aa0, aa1, 1, -1, -1, false, 1)
    KSTEP(5, bb2, aa1, aa0, 1, -1, -1, false, 1)
    KSTEP(6, bb0, aa0, aa1, 1, -1, -1, false, 1)
    KSTEP(7, bb1, aa1, aa0, 1, -1, -1, false, 1)
    KSTEP(8, bb2, aa0, aa1, 0, -1, -1, false, 1)
  }

#undef KSTEP
#undef LDSA
#undef MFMA
#undef WRITE_ONE

  // ---- epilogue: C/D layout col=l&31, row=(r&3)+8*(r>>2)+4*(l>>5) ----
#pragma unroll
  for (int mf = 0; mf < 2; ++mf) {
    int tRow0 = tBase + mf * 32 + 4 * lq;
#pragma unroll
    for (int nf = 0; nf < 3; ++nf) {
      int oCol = oBase + nf * 32 + l31;
#pragma unroll
      for (int r = 0; r < 16; ++r) {
        int rowf = (r & 3) + 8 * (r >> 2);
        out[(size_t)(tRow0 + rowf) * O_DIM + oCol] = acc[mf][nf][r];
      }
    }
  }
}

// ---------------- fallback (no ws): on-the-fly kernel ---------------
__global__ __launch_bounds__(256, 2) void kan_gemm_fb(
    const float* __restrict__ x, const float* __restrict__ bw,
    const float* __restrict__ sw, const float* __restrict__ sc,
    float* __restrict__ out) {
  __shared__ short Alds[128 * 152];
  const int tid  = threadIdx.x;
  const int lane = tid & 63;
  const int wave = tid >> 6;
  const int wm   = wave >> 1;
  const int wn   = wave & 1;
  const int l31  = lane & 31;
  const int lq   = lane >> 5;
  const int tBase = blockIdx.x * 128;
  const int oBase = blockIdx.y * 192 + wn * 96;
  f32x16 acc[2][3];
#pragma unroll
  for (int a = 0; a < 2; ++a)
#pragma unroll
    for (int b = 0; b < 3; ++b)
#pragma unroll
      for (int r = 0; r < 16; ++r) acc[a][b][r] = 0.0f;
  const int sRow = tid >> 1;
  const int sSb  = tid & 1;
  const float* xrow = x + (size_t)(tBase + sRow) * C_DIM + sSb * 8;
  for (int ch = 0; ch < 48; ++ch) {
    __syncthreads();
    const float* xp = xrow + ch * 16;
    flt4 xv0 = *(const flt4*)(xp);
    flt4 xv1 = *(const flt4*)(xp + 4);
    short8 plane[9];
#pragma unroll
    for (int j = 0; j < 8; ++j) {
      float xx  = (j < 4) ? xv0[j] : xv1[j - 4];
      float sig = 1.0f / (1.0f + __expf(-xx));
      plane[0][j] = f2bf(xx * sig);
      float u  = fmaf(xx, 2.5f, 5.5f);
      float fl = floorf(u);
      int   jj = (int)fl;
      float f  = u - fl;
      float f2 = f * f, f3 = f2 * f;
      float W0 = f3 * (1.0f / 6.0f);
      float om = 1.0f - f;
      float W3 = om * om * om * (1.0f / 6.0f);
      float W2 = 0.5f * f3 - f2 + (2.0f / 3.0f);
      float W1 = 1.0f - W0 - W2 - W3;
#pragma unroll
      for (int s = 0; s < 8; ++s) {
        int   dd  = jj - s;
        float v01 = (dd & 1) ? W1 : W0;
        float v23 = (dd & 1) ? W3 : W2;
        float v   = (dd & 2) ? v23 : v01;
        v = ((unsigned)dd < 4u) ? v : 0.0f;
        plane[1 + s][j] = f2bf(v);
      }
    }
    {
      short* arow = &Alds[sRow * 152 + sSb * 72];
#pragma unroll
      for (int g = 0; g < 9; ++g) *(short8*)(arow + g * 8) = plane[g];
    }
    __syncthreads();
    for (int ks = 0; ks < 9; ++ks) {
      const int sGlob = ch * 9 + ks;
      short8 bfr[3];
      const int h    = sGlob * 2 + lq;
      const int cblk = (h * 7282) >> 16;
      const int g    = h - cblk * 9;
      const int cb   = cblk * 8;
#pragma unroll
      for (int nf = 0; nf < 3; ++nf) {
        int col = oBase + nf * 32 + l31;
        const float* rowb = ((g == 0) ? bw : sc) + (size_t)col * C_DIM + cb;
        flt4 s0 = *(const flt4*)rowb;
        flt4 s1 = *(const flt4*)(rowb + 4);
        short8 v;
        if (g == 0) {
#pragma unroll
          for (int j = 0; j < 8; ++j) v[j] = f2bf((j < 4) ? s0[j] : s1[j - 4]);
        } else {
          const float* sp = sw + ((size_t)col * C_DIM + cb) * 8 + (g - 1);
#pragma unroll
          for (int j = 0; j < 8; ++j) {
            float scv = (j < 4) ? s0[j] : s1[j - 4];
            v[j] = f2bf(sp[j * 8] * scv);
          }
        }
        bfr[nf] = v;
      }
      short8 afr[2];
#pragma unroll
      for (int mf = 0; mf < 2; ++mf)
        afr[mf] = *(const short8*)&Alds[(wm * 64 + mf * 32 + l31) * 152 + ks * 16 + lq * 8];
#pragma unroll
      for (int mf = 0; mf < 2; ++mf)
#pragma unroll
        for (int nf = 0; nf < 3; ++nf)
          acc[mf][nf] = __builtin_amdgcn_mfma_f32_32x32x16_bf16(
              afr[mf], bfr[nf], acc[mf][nf], 0, 0, 0);
    }
  }
#pragma unroll
  for (int mf = 0; mf < 2; ++mf) {
    int tRow0 = tBase + wm * 64 + mf * 32 + 4 * lq;
#pragma unroll
    for (int nf = 0; nf < 3; ++nf) {
      int oCol = oBase + nf * 32 + l31;
#pragma unroll
      for (int r = 0; r < 16; ++r) {
        int rowf = (r & 3) + 8 * (r >> 2);
        out[(size_t)(tRow0 + rowf) * O_DIM + oCol] = acc[mf][nf][r];
      }
    }
  }
}

extern "C" void kernel_launch(void* const* d_in, const int* in_sizes, int n_in,
                              void* d_out, int out_size, void* d_ws, size_t ws_size,
                              hipStream_t stream) {
  const float* x  = (const float*)d_in[0];
  const float* bw = (const float*)d_in[1];
  const float* sw = (const float*)d_in[2];
  const float* sc = (const float*)d_in[3];
  float* out = (float*)d_out;

  const bool use_ws = (d_ws != nullptr) && (ws_size >= WT3_BYTES);
  if (use_ws) {
    unsigned short* wt = (unsigned short*)d_ws;
    kan_prep3<<<(O_DIM * C_DIM + 255) / 256, 256, 0, stream>>>(bw, sw, sc, wt);
    kan_gemm12<<<dim3(T_DIM / BM), 512, 0, stream>>>(x, wt, out);
  } else {
    kan_gemm_fb<<<dim3(T_DIM / 128, O_DIM / 192), 256, 0, stream>>>(x, bw, sw, sc, out);
  }
}

// Round 14
// 166.867 us; speedup vs baseline: 1.0462x; 1.0462x over previous
//
#include <hip/hip_runtime.h>

typedef __attribute__((ext_vector_type(8)))  short  short8;
typedef __attribute__((ext_vector_type(16))) float  f32x16;
typedef __attribute__((ext_vector_type(4)))  float  flt4;
typedef __attribute__((ext_vector_type(2)))  float  flt2;
typedef __attribute__((ext_vector_type(4)))  unsigned int u32x4;

#define T_DIM 16384
#define C_DIM 768
#define O_DIM 768

// ---- K layout: per 16-c chunk, 144 k-columns = [16 silu][16c x 8 spline slots]
#define CK2    16
#define CHUNKS 48
#define KSTEPS 9
#define NSG    432            // CHUNKS*KSTEPS
#define LDA3   152            // 144 + 8 pad shorts (304 B row)
#define BM     64
#define BN     768
#define LDSBUF 19456          // BM * 304 bytes per A-buffer
#define WT3_BYTES  ((size_t)NSG * 12288 * 2)

__device__ __forceinline__ unsigned short f2bf(float f) {
  unsigned u = __float_as_uint(f);
  return (unsigned short)((u + 0x7FFFu + ((u >> 16) & 1u)) >> 16);
}

__device__ __forceinline__ unsigned cvtpk(float lo, float hi) {
  unsigned r;
  asm("v_cvt_pk_bf16_f32 %0, %1, %2" : "=v"(r) : "v"(lo), "v"(hi));
  return r;
}

// lgkmcnt-only barrier: ds_writes drained & visible, but B/x register prefetch
// (wave-private vmem) stays IN FLIGHT across the barrier — avoids the
// __syncthreads vmcnt(0) drain (m97's ~20% stall pattern).
#define CHUNK_BARRIER()                                                  \
  {                                                                      \
    asm volatile("s_waitcnt lgkmcnt(0)" ::: "memory");                   \
    __builtin_amdgcn_s_barrier();                                        \
    asm volatile("" ::: "memory");                                       \
  }

// ---------------- prep: combined bf16 weights, fragment-major ---------------
// k_silu(c)     = (c>>4)*144 + (c&15)
// k_spline(c,s) = (c>>4)*144 + 16 + (c&15)*8 + s
// phys short index = (k>>4)*12288 + o*16 + (k&15)
__global__ void kan_prep3(const float* __restrict__ bw, const float* __restrict__ sw,
                          const float* __restrict__ sc, unsigned short* __restrict__ wt) {
  int id = blockIdx.x * 256 + threadIdx.x;
  if (id >= O_DIM * C_DIM) return;
  int o = id / C_DIM;
  int c = id - o * C_DIM;
  float b = bw[id];
  float s = sc[id];
  const float* sp = sw + (size_t)id * 8;
  {
    int k = (c >> 4) * 144 + (c & 15);
    wt[(size_t)(k >> 4) * 12288 + o * 16 + (k & 15)] = f2bf(b);
  }
#pragma unroll
  for (int g = 0; g < 8; ++g) {
    int k = (c >> 4) * 144 + 16 + (c & 15) * 8 + g;
    wt[(size_t)(k >> 4) * 12288 + o * 16 + (k & 15)] = f2bf(sp[g] * s);
  }
}

// ---------------- fused GEMM (ws path) --------------------------------------
// EXACT round-9 structure (best: 167us): 512 threads = 8 waves of 64x96; block
// tile 64x768 (full O); grid 256 = 1 block/CU; x staged exactly once; depth-3
// B register rotation; setprio around MFMA cluster.
// ONLY change: in-loop barriers are lgkmcnt-only (CHUNK_BARRIER).
__global__ __launch_bounds__(512, 2) void kan_gemm13(
    const float* __restrict__ x, const unsigned short* __restrict__ wt,
    float* __restrict__ out) {
  __shared__ short Alds[2 * BM * LDA3];   // 38912 B

  const int tid  = threadIdx.x;
  const int lane = tid & 63;
  const int wn   = tid >> 6;            // wave 0..7 -> 96-col slab
  const int l31  = lane & 31;
  const int lq   = lane >> 5;

  const int d  = blockIdx.x;            // 0..255
  const int tBase = d * BM;
  const int oBase = wn * 96;

  f32x16 acc[2][3];
#pragma unroll
  for (int a = 0; a < 2; ++a)
#pragma unroll
    for (int b = 0; b < 3; ++b)
#pragma unroll
      for (int r = 0; r < 16; ++r) acc[a][b][r] = 0.0f;

  // staging: thread -> (row 0..63, 2-col pair); 2 elements per chunk
  const int sRow = tid >> 3;            // 0..63
  const int sSb  = tid & 7;             // 0..7  -> c pair sSb*2 + {0,1}
  const float* xrow = x + (size_t)(tBase + sRow) * C_DIM + sSb * 2;

  char* ldsB = (char*)Alds;
  const int wbase = sRow * 304;
  int rbyte[2];
#pragma unroll
  for (int mf = 0; mf < 2; ++mf)
    rbyte[mf] = (mf * 32 + l31) * 304 + lq * 16;

  flt2 xa = *(const flt2*)(xrow);       // x for chunk 0
  float    su[2];                       // silu values (2 c)
  unsigned sww[8];                      // spline words, 4 per c

  auto stage_j = [&](int j) {
    float xx  = xa[j];
    float ex  = __expf(-xx);
    float sig = __builtin_amdgcn_rcpf(1.0f + ex);
    su[j] = xx * sig;
    float u  = fmaf(xx, 2.5f, 5.5f);
    float fl = floorf(u);
    int   jj = (int)fl;
    float f  = u - fl;
    float f2 = f * f, f3 = f2 * f;
    float W0 = f3 * (1.0f / 6.0f);
    float om = 1.0f - f;
    float W3 = om * om * om * (1.0f / 6.0f);
    float W2 = 0.5f * f3 - f2 + (2.0f / 3.0f);
    float W1 = 1.0f - W0 - W2 - W3;
    unsigned V0 = cvtpk(W3, W2);
    unsigned V1 = cvtpk(W1, W0);
    unsigned A0 = V0 << 16;
    unsigned A1 = (V1 << 16) | (V0 >> 16);
    unsigned A2 = V1 >> 16;
    int  k = jj - 3;
    int  q = k >> 1;
    bool r = (k & 1) != 0;
    unsigned U0 = r ? A0 : V0;
    unsigned U1 = r ? A1 : V1;
    unsigned U2 = r ? A2 : 0u;
#pragma unroll
    for (int p = 0; p < 4; ++p)
      sww[4 * j + p] =
          (q == p) ? U0 : ((q == p - 1) ? U1 : ((q == p - 2) ? U2 : 0u));
  };

// WR=0: silu b32 (2 shorts); WR=1: spline b128 c0; WR=2: spline b128 c1
#define WRITE_ONE(WR, WOFF)                                             \
  {                                                                     \
    if ((WR) == 0) {                                                    \
      *(unsigned*)(ldsB + (WOFF) + wbase + sSb * 4) = cvtpk(su[0], su[1]); \
    } else {                                                            \
      u32x4 t;                                                          \
      t.x = sww[4 * ((WR) - 1)];     t.y = sww[4 * ((WR) - 1) + 1];     \
      t.z = sww[4 * ((WR) - 1) + 2]; t.w = sww[4 * ((WR) - 1) + 3];     \
      *(u32x4*)(ldsB + (WOFF) + wbase + 32 + sSb * 32 + ((WR) - 1) * 16) = t; \
    }                                                                   \
  }

  // ---- prologue: stage chunk 0 into buf 0, prefetch x(ch1), B sg0/1/2 ----
  stage_j(0); stage_j(1);
  WRITE_ONE(0, 0) WRITE_ONE(1, 0) WRITE_ONE(2, 0)
  xa = *(const flt2*)(xrow + CK2);

  const size_t lofs = (size_t)(oBase + l31) * 16 + lq * 8;
  short8 bb0[3], bb1[3], bb2[3];
  {
    const unsigned short* w0 = wt + lofs;
    bb0[0] = *(const short8*)(w0);
    bb0[1] = *(const short8*)(w0 + 512);
    bb0[2] = *(const short8*)(w0 + 1024);
    const unsigned short* w1 = wt + 12288 + lofs;
    bb1[0] = *(const short8*)(w1);
    bb1[1] = *(const short8*)(w1 + 512);
    bb1[2] = *(const short8*)(w1 + 1024);
    const unsigned short* w2 = wt + 24576 + lofs;
    bb2[0] = *(const short8*)(w2);
    bb2[1] = *(const short8*)(w2 + 512);
    bb2[2] = *(const short8*)(w2 + 1024);
  }
  __syncthreads();

#define LDSA(MF, KS) (*(const short8*)(ldsB + roff + rbyte[MF] + (KS) * 32))
#define MFMA(A, B, C) __builtin_amdgcn_mfma_f32_32x32x16_bf16((A), (B), (C), 0, 0, 0)

  short8 aa0[2], aa1[2];

// KSTEP (round-9 form): [read A(ks+1)] -> 6 MFMA (setprio) -> B load sg+3 ->
//        [ds_write] -> [stage_j] -> [x prefetch]
#define KSTEP(KS, BB, AAC, AAN, DOREAD, SJ, WR, DOX, GUARD)              \
  {                                                                      \
    if (DOREAD) {                                                        \
      AAN[0] = LDSA(0, (KS) + 1);                                        \
      AAN[1] = LDSA(1, (KS) + 1);                                        \
    }                                                                    \
    __builtin_amdgcn_s_setprio(1);                                       \
    acc[0][0] = MFMA(AAC[0], BB[0], acc[0][0]);                          \
    acc[0][1] = MFMA(AAC[0], BB[1], acc[0][1]);                          \
    acc[0][2] = MFMA(AAC[0], BB[2], acc[0][2]);                          \
    acc[1][0] = MFMA(AAC[1], BB[0], acc[1][0]);                          \
    acc[1][1] = MFMA(AAC[1], BB[1], acc[1][1]);                          \
    acc[1][2] = MFMA(AAC[1], BB[2], acc[1][2]);                          \
    __builtin_amdgcn_s_setprio(0);                                       \
    if (!(GUARD) || (chBase + (KS) + 3 < NSG)) {                         \
      const unsigned short* wp =                                         \
          wt + (size_t)(chBase + (KS) + 3) * 12288 + lofs;               \
      BB[0] = *(const short8*)(wp);                                      \
      BB[1] = *(const short8*)(wp + 512);                                \
      BB[2] = *(const short8*)(wp + 1024);                               \
    }                                                                    \
    if ((WR) >= 0) WRITE_ONE(WR, woff)                                   \
    if ((SJ) >= 0) stage_j(SJ);                                          \
    if (DOX) xa = *(const flt2*)(xrow + (ch + 2) * CK2);                 \
  }

  // ---- main loop: chunks 0..46; stage ch+1 into other buffer; 1 barrier ----
  for (int ch = 0; ch < CHUNKS - 1; ++ch) {
    const int chBase = ch * KSTEPS;
    const int roff   = (ch & 1) * LDSBUF;
    const int woff   = roff ^ LDSBUF;
    const bool dox   = (ch + 2 < CHUNKS);
    aa0[0] = LDSA(0, 0);
    aa0[1] = LDSA(1, 0);
    KSTEP(0, bb0, aa0, aa1, 1,  0, -1, false, 0)
    KSTEP(1, bb1, aa1, aa0, 1,  1, -1, false, 0)
    KSTEP(2, bb2, aa0, aa1, 1, -1, -1, dox,   0)
    KSTEP(3, bb0, aa1, aa0, 1, -1, -1, false, 0)
    KSTEP(4, bb1, aa0, aa1, 1, -1,  0, false, 0)
    KSTEP(5, bb2, aa1, aa0, 1, -1,  1, false, 0)
    KSTEP(6, bb0, aa0, aa1, 1, -1,  2, false, 0)
    KSTEP(7, bb1, aa1, aa0, 1, -1, -1, false, 0)
    KSTEP(8, bb2, aa0, aa1, 0, -1, -1, false, 0)
    CHUNK_BARRIER()
  }
  // ---- last chunk (reads buf 1; no staging; guard tail B loads) ----
  {
    const int ch     = CHUNKS - 1;
    (void)ch;
    const int chBase = (CHUNKS - 1) * KSTEPS;
    const int roff   = ((CHUNKS - 1) & 1) * LDSBUF;
    const int woff   = 0;  // unused (no WR in tail)
    (void)woff;
    aa0[0] = LDSA(0, 0);
    aa0[1] = LDSA(1, 0);
    KSTEP(0, bb0, aa0, aa1, 1, -1, -1, false, 1)
    KSTEP(1, bb1, aa1, aa0, 1, -1, -1, false, 1)
    KSTEP(2, bb2, aa0, aa1, 1, -1, -1, false, 1)
    KSTEP(3, bb0, aa1, aa0, 1, -1, -1, false, 1)
    KSTEP(4, bb1, aa0, aa1, 1, -1, -1, false, 1)
    KSTEP(5, bb2, aa1, aa0, 1, -1, -1, false, 1)
    KSTEP(6, bb0, aa0, aa1, 1, -1, -1, false, 1)
    KSTEP(7, bb1, aa1, aa0, 1, -1, -1, false, 1)
    KSTEP(8, bb2, aa0, aa1, 0, -1, -1, false, 1)
  }

#undef KSTEP
#undef LDSA
#undef MFMA
#undef WRITE_ONE

  // ---- epilogue: C/D layout col=l&31, row=(r&3)+8*(r>>2)+4*(l>>5) ----
#pragma unroll
  for (int mf = 0; mf < 2; ++mf) {
    int tRow0 = tBase + mf * 32 + 4 * lq;
#pragma unroll
    for (int nf = 0; nf < 3; ++nf) {
      int oCol = oBase + nf * 32 + l31;
#pragma unroll
      for (int r = 0; r < 16; ++r) {
        int rowf = (r & 3) + 8 * (r >> 2);
        out[(size_t)(tRow0 + rowf) * O_DIM + oCol] = acc[mf][nf][r];
      }
    }
  }
}

// ---------------- fallback (no ws): on-the-fly kernel ---------------
__global__ __launch_bounds__(256, 2) void kan_gemm_fb(
    const float* __restrict__ x, const float* __restrict__ bw,
    const float* __restrict__ sw, const float* __restrict__ sc,
    float* __restrict__ out) {
  __shared__ short Alds[128 * 152];
  const int tid  = threadIdx.x;
  const int lane = tid & 63;
  const int wave = tid >> 6;
  const int wm   = wave >> 1;
  const int wn   = wave & 1;
  const int l31  = lane & 31;
  const int lq   = lane >> 5;
  const int tBase = blockIdx.x * 128;
  const int oBase = blockIdx.y * 192 + wn * 96;
  f32x16 acc[2][3];
#pragma unroll
  for (int a = 0; a < 2; ++a)
#pragma unroll
    for (int b = 0; b < 3; ++b)
#pragma unroll
      for (int r = 0; r < 16; ++r) acc[a][b][r] = 0.0f;
  const int sRow = tid >> 1;
  const int sSb  = tid & 1;
  const float* xrow = x + (size_t)(tBase + sRow) * C_DIM + sSb * 8;
  for (int ch = 0; ch < 48; ++ch) {
    __syncthreads();
    const float* xp = xrow + ch * 16;
    flt4 xv0 = *(const flt4*)(xp);
    flt4 xv1 = *(const flt4*)(xp + 4);
    short8 plane[9];
#pragma unroll
    for (int j = 0; j < 8; ++j) {
      float xx  = (j < 4) ? xv0[j] : xv1[j - 4];
      float sig = 1.0f / (1.0f + __expf(-xx));
      plane[0][j] = f2bf(xx * sig);
      float u  = fmaf(xx, 2.5f, 5.5f);
      float fl = floorf(u);
      int   jj = (int)fl;
      float f  = u - fl;
      float f2 = f * f, f3 = f2 * f;
      float W0 = f3 * (1.0f / 6.0f);
      float om = 1.0f - f;
      float W3 = om * om * om * (1.0f / 6.0f);
      float W2 = 0.5f * f3 - f2 + (2.0f / 3.0f);
      float W1 = 1.0f - W0 - W2 - W3;
#pragma unroll
      for (int s = 0; s < 8; ++s) {
        int   dd  = jj - s;
        float v01 = (dd & 1) ? W1 : W0;
        float v23 = (dd & 1) ? W3 : W2;
        float v   = (dd & 2) ? v23 : v01;
        v = ((unsigned)dd < 4u) ? v : 0.0f;
        plane[1 + s][j] = f2bf(v);
      }
    }
    {
      short* arow = &Alds[sRow * 152 + sSb * 72];
#pragma unroll
      for (int g = 0; g < 9; ++g) *(short8*)(arow + g * 8) = plane[g];
    }
    __syncthreads();
    for (int ks = 0; ks < 9; ++ks) {
      const int sGlob = ch * 9 + ks;
      short8 bfr[3];
      const int h    = sGlob * 2 + lq;
      const int cblk = (h * 7282) >> 16;
      const int g    = h - cblk * 9;
      const int cb   = cblk * 8;
#pragma unroll
      for (int nf = 0; nf < 3; ++nf) {
        int col = oBase + nf * 32 + l31;
        const float* rowb = ((g == 0) ? bw : sc) + (size_t)col * C_DIM + cb;
        flt4 s0 = *(const flt4*)rowb;
        flt4 s1 = *(const flt4*)(rowb + 4);
        short8 v;
        if (g == 0) {
#pragma unroll
          for (int j = 0; j < 8; ++j) v[j] = f2bf((j < 4) ? s0[j] : s1[j - 4]);
        } else {
          const float* sp = sw + ((size_t)col * C_DIM + cb) * 8 + (g - 1);
#pragma unroll
          for (int j = 0; j < 8; ++j) {
            float scv = (j < 4) ? s0[j] : s1[j - 4];
            v[j] = f2bf(sp[j * 8] * scv);
          }
        }
        bfr[nf] = v;
      }
      short8 afr[2];
#pragma unroll
      for (int mf = 0; mf < 2; ++mf)
        afr[mf] = *(const short8*)&Alds[(wm * 64 + mf * 32 + l31) * 152 + ks * 16 + lq * 8];
#pragma unroll
      for (int mf = 0; mf < 2; ++mf)
#pragma unroll
        for (int nf = 0; nf < 3; ++nf)
          acc[mf][nf] = __builtin_amdgcn_mfma_f32_32x32x16_bf16(
              afr[mf], bfr[nf], acc[mf][nf], 0, 0, 0);
    }
  }
#pragma unroll
  for (int mf = 0; mf < 2; ++mf) {
    int tRow0 = tBase + wm * 64 + mf * 32 + 4 * lq;
#pragma unroll
    for (int nf = 0; nf < 3; ++nf) {
      int oCol = oBase + nf * 32 + l31;
#pragma unroll
      for (int r = 0; r < 16; ++r) {
        int rowf = (r & 3) + 8 * (r >> 2);
        out[(size_t)(tRow0 + rowf) * O_DIM + oCol] = acc[mf][nf][r];
      }
    }
  }
}

extern "C" void kernel_launch(void* const* d_in, const int* in_sizes, int n_in,
                              void* d_out, int out_size, void* d_ws, size_t ws_size,
                              hipStream_t stream) {
  const float* x  = (const float*)d_in[0];
  const float* bw = (const float*)d_in[1];
  const float* sw = (const float*)d_in[2];
  const float* sc = (const float*)d_in[3];
  float* out = (float*)d_out;

  const bool use_ws = (d_ws != nullptr) && (ws_size >= WT3_BYTES);
  if (use_ws) {
    unsigned short* wt = (unsigned short*)d_ws;
    kan_prep3<<<(O_DIM * C_DIM + 255) / 256, 256, 0, stream>>>(bw, sw, sc, wt);
    kan_gemm13<<<dim3(T_DIM / BM), 512, 0, stream>>>(x, wt, out);
  } else {
    kan_gemm_fb<<<dim3(T_DIM / 128, O_DIM / 192), 256, 0, stream>>>(x, bw, sw, sc, out);
  }
}